// Round 1
// baseline (247.697 us; speedup 1.0000x reference)
//
#include <hip/hip_runtime.h>

// StrictProjectionBlock: per-3x3-matrix Frobenius normalize + 4 Newton-Schulz
// layers. dur_us decomposition: ~173us harness poison fills (fixed) + kernel.
// R1-R3 history: algebra reduced to Q' = Q*M, M = (0.5N-1.5I)N + 2I (symmetric,
// 6 entries); separate in/out LDS buffers (2 barriers); nontemporal stores.
// Kernel was ~73us vs a 288MB @ 6.3TB/s copy floor of ~46us.
//
// R4 theory: occupancy-limited overlap. Suspected VGPR>64 -> 16 waves/CU ->
// load-latency + block-turnover exposed. Changes:
//  * __launch_bounds__(256, 8): cap VGPR at 64 -> 8 blocks/CU = 32 waves/CU
//    (LDS 18.4KB x 8 = 147KB <= 160KB, exactly at the wave cap).
//  * async global->LDS staging via __builtin_amdgcn_global_load_lds width=16:
//    no VGPR round-trip, no ds_write; LDS dest is wave-uniform base + lane*16
//    (our layout is linear, so the HW pattern matches exactly).
//  * M kept as 6 named scalars (symmetric), no [3][3] array.
//
// Layout: one thread per matrix; coalesced float4 global<->LDS staging;
// stride-9 LDS per-thread access is a bank permutation (gcd(9,32)=1) -> only
// the free 2-way wave64 aliasing (measured SQ_LDS_BANK_CONFLICT = 0).
// 4,000,000 % 256 == 0 -> 15625 blocks, no tail.

#define NLAYERS 4

typedef float v4f __attribute__((ext_vector_type(4)));
typedef const __attribute__((address_space(1))) v4f gv4f_t;
typedef __attribute__((address_space(3))) v4f lv4f_t;

__global__ __launch_bounds__(256, 8) void
proj_kernel(const float* __restrict__ x, float* __restrict__ out) {
    __shared__ float lin[256 * 9];               // 9216 B
    __shared__ float lout[256 * 9];              // 9216 B
    const int tid = threadIdx.x;
    const long long mbase = (long long)blockIdx.x * 256;

    // ---- async stage 2304 floats = 576 float4 direct to LDS ----
    // global_load_lds writes base + lane*16; pass each wave's slot base.
    const v4f* __restrict__ gin = (const v4f*)(x + mbase * 9);
    v4f* lin4 = (v4f*)lin;
    const int wslot = tid & ~63;                 // wave-uniform LDS slot base
    __builtin_amdgcn_global_load_lds((gv4f_t*)(gin + tid),
                                     (lv4f_t*)(lin4 + wslot), 16, 0, 0);
    __builtin_amdgcn_global_load_lds((gv4f_t*)(gin + 256 + tid),
                                     (lv4f_t*)(lin4 + 256 + wslot), 16, 0, 0);
    if (tid < 64)                                // wave 0 only: uniform branch
        __builtin_amdgcn_global_load_lds((gv4f_t*)(gin + 512 + tid),
                                         (lv4f_t*)(lin4 + 512), 16, 0, 0);
    __syncthreads();                             // drains vmcnt before reads

    // ---- per-thread matrix into registers ----
    float q[9];
#pragma unroll
    for (int k = 0; k < 9; ++k) q[k] = lin[tid * 9 + k];

    // ---- Frobenius normalize ----
    float s = 0.f;
#pragma unroll
    for (int k = 0; k < 9; ++k) s = __builtin_fmaf(q[k], q[k], s);
    const float inv = rsqrtf(s);
#pragma unroll
    for (int k = 0; k < 9; ++k) q[k] *= inv;

    // ---- 4 Newton-Schulz layers: Q <- Q * ((0.5N - 1.5I)N + 2I) ----
#pragma unroll
    for (int layer = 0; layer < NLAYERS; ++layer) {
        // N = Q^T Q (symmetric, 6 entries)
        const float n00 = q[0]*q[0] + q[3]*q[3] + q[6]*q[6];
        const float n01 = q[0]*q[1] + q[3]*q[4] + q[6]*q[7];
        const float n02 = q[0]*q[2] + q[3]*q[5] + q[6]*q[8];
        const float n11 = q[1]*q[1] + q[4]*q[4] + q[7]*q[7];
        const float n12 = q[1]*q[2] + q[4]*q[5] + q[7]*q[8];
        const float n22 = q[2]*q[2] + q[5]*q[5] + q[8]*q[8];

        // A = 0.5*N - 1.5*I (symmetric)
        const float a00 = __builtin_fmaf(0.5f, n00, -1.5f);
        const float a11 = __builtin_fmaf(0.5f, n11, -1.5f);
        const float a22 = __builtin_fmaf(0.5f, n22, -1.5f);
        const float a01 = 0.5f * n01;
        const float a02 = 0.5f * n02;
        const float a12 = 0.5f * n12;

        // M = A*N + 2I (symmetric since A = p(N) commutes with N);
        // diag +2 folded into the fma accumulator start.
        const float m00 = __builtin_fmaf(a00,n00, __builtin_fmaf(a01,n01, __builtin_fmaf(a02,n02, 2.0f)));
        const float m01 = __builtin_fmaf(a00,n01, __builtin_fmaf(a01,n11, a02*n12));
        const float m02 = __builtin_fmaf(a00,n02, __builtin_fmaf(a01,n12, a02*n22));
        const float m11 = __builtin_fmaf(a01,n01, __builtin_fmaf(a11,n11, __builtin_fmaf(a12,n12, 2.0f)));
        const float m12 = __builtin_fmaf(a01,n02, __builtin_fmaf(a11,n12, a12*n22));
        const float m22 = __builtin_fmaf(a02,n02, __builtin_fmaf(a12,n12, __builtin_fmaf(a22,n22, 2.0f)));

        // Q <- Q * M (M symmetric: 6 scalars, fully unrolled, const indices)
        float qn[9];
#pragma unroll
        for (int i = 0; i < 3; ++i) {
            const float q0 = q[3*i], q1 = q[3*i+1], q2 = q[3*i+2];
            qn[3*i+0] = __builtin_fmaf(q0, m00, __builtin_fmaf(q1, m01, q2 * m02));
            qn[3*i+1] = __builtin_fmaf(q0, m01, __builtin_fmaf(q1, m11, q2 * m12));
            qn[3*i+2] = __builtin_fmaf(q0, m02, __builtin_fmaf(q1, m12, q2 * m22));
        }
#pragma unroll
        for (int k = 0; k < 9; ++k) q[k] = qn[k];
    }

    // ---- write back through the second LDS buffer ----
#pragma unroll
    for (int k = 0; k < 9; ++k) lout[tid * 9 + k] = q[k];
    __syncthreads();

    // ---- coalesced nontemporal float4 stores ----
    v4f* __restrict__ gout = (v4f*)(out + mbase * 9);
    const v4f* lout4 = (const v4f*)lout;
    __builtin_nontemporal_store(lout4[tid],       gout + tid);
    __builtin_nontemporal_store(lout4[tid + 256], gout + tid + 256);
    if (tid < 64)
        __builtin_nontemporal_store(lout4[tid + 512], gout + tid + 512);
}

extern "C" void kernel_launch(void* const* d_in, const int* in_sizes, int n_in,
                              void* d_out, int out_size, void* d_ws, size_t ws_size,
                              hipStream_t stream) {
    const float* x = (const float*)d_in[0];
    float* out = (float*)d_out;
    const int nmat = in_sizes[0] / 9;        // 4,000,000
    const int blocks = nmat / 256;           // 15625 (exact)
    proj_kernel<<<blocks, 256, 0, stream>>>(x, out);
}